// Round 2
// 469.699 us; speedup vs baseline: 1.1556x; 1.1556x over previous
//
#include <hip/hip_runtime.h>
#include <hip/hip_bf16.h>
#include <stdint.h>

#define M_DIM 8192
#define K_DIM 4096
#define N_DIM 4096

typedef __attribute__((ext_vector_type(8))) short short8;
typedef __attribute__((ext_vector_type(4))) float floatx4;

// ---------------- fused per-row abs-mean scale + ternary quantize ----------------
__global__ void fused_scale_quant(const float* __restrict__ w, float* __restrict__ scales,
                                  __hip_bfloat16* __restrict__ qb) {
    int row = blockIdx.x;
    const float4* wr = (const float4*)(w + (size_t)row * K_DIM);
    float4 v[4];
    double s = 0.0;
    #pragma unroll
    for (int i = 0; i < 4; i++) {
        v[i] = wr[threadIdx.x + 256 * i];
        s += (double)fabsf(v[i].x) + (double)fabsf(v[i].y) +
             (double)fabsf(v[i].z) + (double)fabsf(v[i].w);
    }
    #pragma unroll
    for (int off = 32; off > 0; off >>= 1) s += __shfl_down(s, off);
    __shared__ double partial[4];
    __shared__ float s_scale;
    int wave = threadIdx.x >> 6;
    if ((threadIdx.x & 63) == 0) partial[wave] = s;
    __syncthreads();
    if (threadIdx.x == 0) {
        double t = partial[0] + partial[1] + partial[2] + partial[3];
        float m = (float)(t / (double)K_DIM);
        m = fmaxf(m, 1e-5f);
        scales[row] = m;
        s_scale = m;
    }
    __syncthreads();
    float sc = s_scale;
    __hip_bfloat16* qr = qb + (size_t)row * K_DIM;
    #pragma unroll
    for (int i = 0; i < 4; i++) {
        float q0 = fminf(fmaxf(rintf(v[i].x / sc), -1.f), 1.f);
        float q1 = fminf(fmaxf(rintf(v[i].y / sc), -1.f), 1.f);
        float q2 = fminf(fmaxf(rintf(v[i].z / sc), -1.f), 1.f);
        float q3 = fminf(fmaxf(rintf(v[i].w / sc), -1.f), 1.f);
        __hip_bfloat16 o[4] = {__float2bfloat16(q0), __float2bfloat16(q1),
                               __float2bfloat16(q2), __float2bfloat16(q3)};
        *(uint2*)(qr + 4 * (threadIdx.x + 256 * i)) = *(uint2*)o;
    }
}

// ---------------- x fp32 -> bf16 ----------------
__global__ void xconv_kernel(const float* __restrict__ x, __hip_bfloat16* __restrict__ xb) {
    size_t v = (size_t)blockIdx.x * blockDim.x + threadIdx.x;
    float4 a = ((const float4*)x)[2 * v];
    float4 b = ((const float4*)x)[2 * v + 1];
    __hip_bfloat16 o[8] = {__float2bfloat16(a.x), __float2bfloat16(a.y),
                           __float2bfloat16(a.z), __float2bfloat16(a.w),
                           __float2bfloat16(b.x), __float2bfloat16(b.y),
                           __float2bfloat16(b.z), __float2bfloat16(b.w)};
    *(uint4*)(xb + 8 * v) = *(uint4*)o;
}

// ---------------- 256x256 8-phase counted-vmcnt bf16 MFMA GEMM ----------------
__device__ __forceinline__ void load16(const void* g, void* l) {
    __builtin_amdgcn_global_load_lds((const __attribute__((address_space(1))) uint32_t*)g,
                                     (__attribute__((address_space(3))) uint32_t*)l, 16, 0, 0);
}

#define BARRIER() do { asm volatile("" ::: "memory"); __builtin_amdgcn_s_barrier(); asm volatile("" ::: "memory"); } while (0)
#define VM4 asm volatile("s_waitcnt vmcnt(4)" ::: "memory")
#define VM0 asm volatile("s_waitcnt vmcnt(0)" ::: "memory")
#define MID() do { BARRIER(); asm volatile("s_waitcnt lgkmcnt(0)" ::: "memory"); __builtin_amdgcn_sched_barrier(0); } while (0)

// LDS map (128 KiB): buf d at d*65536; A half ha at +ha*16384; B half hb at +32768+hb*16384.
// Within a half (128 rows x 64 bf16): chunk p (16B) at p*16, p = row*8 + (chunk ^ (row&7)).
// global_load_lds dest is linear (tid*16); the XOR swizzle is applied to the GLOBAL source
// (inverse) and to the ds_read address (forward) — rule #21 both-sides.

#define STAGE_A0(d, t) do { load16(gA00 + (t)*64, ldsw + (d)*65536);          load16(gA01 + (t)*64, ldsw + (d)*65536 + 8192); } while (0)
#define STAGE_A1(d, t) do { load16(gA10 + (t)*64, ldsw + (d)*65536 + 16384);  load16(gA11 + (t)*64, ldsw + (d)*65536 + 24576); } while (0)
#define STAGE_B0(d, t) do { load16(gB00 + (t)*64, ldsw + (d)*65536 + 32768);  load16(gB01 + (t)*64, ldsw + (d)*65536 + 40960); } while (0)
#define STAGE_B1(d, t) do { load16(gB10 + (t)*64, ldsw + (d)*65536 + 49152);  load16(gB11 + (t)*64, ldsw + (d)*65536 + 57344); } while (0)

#define DS_READ_A(CUR, HA) do { \
    _Pragma("unroll") for (int mi_ = 0; mi_ < 4; ++mi_) { \
        aF[0][mi_] = *(const short8*)(lds + (CUR)*65536 + (HA)*16384 + aoff0 + mi_*2048); \
        aF[1][mi_] = *(const short8*)(lds + (CUR)*65536 + (HA)*16384 + aoff1 + mi_*2048); \
    } } while (0)

#define DS_READ_B(CUR, HB) do { \
    _Pragma("unroll") for (int ni_ = 0; ni_ < 2; ++ni_) { \
        bF[0][ni_] = *(const short8*)(lds + (CUR)*65536 + 32768 + (HB)*16384 + boff0 + ni_*2048); \
        bF[1][ni_] = *(const short8*)(lds + (CUR)*65536 + 32768 + (HB)*16384 + boff1 + ni_*2048); \
    } } while (0)

#define MFMA_CLUSTER(HA, HB) do { \
    __builtin_amdgcn_s_setprio(1); \
    _Pragma("unroll") for (int mi_ = 0; mi_ < 4; ++mi_) \
    _Pragma("unroll") for (int ni_ = 0; ni_ < 2; ++ni_) \
        acc[HA][HB][mi_][ni_] = __builtin_amdgcn_mfma_f32_16x16x32_bf16(aF[0][mi_], bF[0][ni_], acc[HA][HB][mi_][ni_], 0, 0, 0); \
    _Pragma("unroll") for (int mi_ = 0; mi_ < 4; ++mi_) \
    _Pragma("unroll") for (int ni_ = 0; ni_ < 2; ++ni_) \
        acc[HA][HB][mi_][ni_] = __builtin_amdgcn_mfma_f32_16x16x32_bf16(aF[1][mi_], bF[1][ni_], acc[HA][HB][mi_][ni_], 0, 0, 0); \
    __builtin_amdgcn_s_setprio(0); \
    __builtin_amdgcn_sched_barrier(0); \
} while (0)

// phase p: compute quarter (ha,hb) of K-tile CUR; issue one half of a future K-tile.
// hazard graph (verified): every overwrite-issue is >=1 full barrier after the slot's
// last ds_read; boundary vmcnt(4)+barrier certifies the NEXT tile's 4 halves resident.
#define FULL_TILE(CUR, SP0, SP1, SP2, SP3, BVM) do { \
    DS_READ_A(CUR, 0); DS_READ_B(CUR, 0); SP0; MID(); MFMA_CLUSTER(0, 0); BARRIER(); \
    DS_READ_B(CUR, 1);                    SP1; MID(); MFMA_CLUSTER(0, 1); BARRIER(); \
    DS_READ_A(CUR, 1); DS_READ_B(CUR, 0); SP2; MID(); MFMA_CLUSTER(1, 0); BARRIER(); \
    DS_READ_B(CUR, 1);                    SP3; BVM; MID(); MFMA_CLUSTER(1, 1); BARRIER(); \
} while (0)

__global__ __launch_bounds__(512, 1) void gemm_kernel(const __hip_bfloat16* __restrict__ xb,
                                                      const __hip_bfloat16* __restrict__ qb,
                                                      const float* __restrict__ scales,
                                                      float* __restrict__ out) {
    __shared__ __align__(16) char smem[131072];
    char* lds = smem;
    const int tid = threadIdx.x;
    const int lane = tid & 63;
    const int wave = tid >> 6;
    const int wr = wave >> 2;   // 2 wave-rows
    const int wc = wave & 3;    // 4 wave-cols

    // XCD swizzle: 512 wgs, 8 XCDs, 64 contiguous per XCD (bijective, 512%8==0)
    int bid = blockIdx.x;
    int swz = (bid & 7) * 64 + (bid >> 3);
    const int m0 = (swz >> 4) * 256;
    const int n0 = (swz & 15) * 256;

    // staging source (inverse-swizzled): thread covers chunks tid and tid+512 of each half
    const int r0 = tid >> 3,         c0 = (tid & 7) ^ (r0 & 7);
    const int r1 = (tid + 512) >> 3, c1 = ((tid + 512) & 7) ^ (r1 & 7);
    const __hip_bfloat16* gA00 = xb + (size_t)(m0 + r0) * K_DIM + c0 * 8;
    const __hip_bfloat16* gA01 = xb + (size_t)(m0 + r1) * K_DIM + c1 * 8;
    const __hip_bfloat16* gA10 = gA00 + (size_t)128 * K_DIM;
    const __hip_bfloat16* gA11 = gA01 + (size_t)128 * K_DIM;
    const __hip_bfloat16* gB00 = qb + (size_t)(n0 + r0) * K_DIM + c0 * 8;
    const __hip_bfloat16* gB01 = qb + (size_t)(n0 + r1) * K_DIM + c1 * 8;
    const __hip_bfloat16* gB10 = gB00 + (size_t)128 * K_DIM;
    const __hip_bfloat16* gB11 = gB01 + (size_t)128 * K_DIM;
    char* ldsw = lds + tid * 16;

    // ds_read offsets: row = 64*wr + 16*mi + lr (A) / 32*wc + 16*ni + lr (B);
    // (row&7)==(lane&7) since the base terms are multiples of 8 -> swizzle lane-only.
    const int lr = lane & 15, lq = lane >> 4, l7 = lane & 7;
    const int sw0 = (lq ^ l7) * 16;
    const int sw1 = ((4 + lq) ^ l7) * 16;
    const int aoff0 = (wr * 64 + lr) * 128 + sw0;
    const int aoff1 = (wr * 64 + lr) * 128 + sw1;
    const int boff0 = (wc * 32 + lr) * 128 + sw0;
    const int boff1 = (wc * 32 + lr) * 128 + sw1;

    floatx4 acc[2][2][4][2] = {};   // [ha][hb][mi][ni] — 128 VGPRs
    short8 aF[2][4], bF[2][2];      // [kk][mi] / [kk][ni]

    // prologue: prime stream H0..H5 = A0,B0,B1,A1(t0), A0,B0(t1); tile0 resident after vmcnt(4)
    STAGE_A0(0, 0); STAGE_B0(0, 0); STAGE_B1(0, 0); STAGE_A1(0, 0);
    STAGE_A0(1, 1); STAGE_B0(1, 1);
    VM4;
    BARRIER();

    // main: 31 iters x 2 K-tiles; issues: p0->B1(kt+1), p1->A1(kt+1), p2->A0(kt+2), p3->B0(kt+2)
    #pragma unroll 1
    for (int it = 0; it < 31; ++it) {
        const int kt0 = 2 * it;
        FULL_TILE(0, STAGE_B1(1, kt0 + 1), STAGE_A1(1, kt0 + 1),
                     STAGE_A0(0, kt0 + 2), STAGE_B0(0, kt0 + 2), VM4);
        FULL_TILE(1, STAGE_B1(0, kt0 + 2), STAGE_A1(0, kt0 + 2),
                     STAGE_A0(1, kt0 + 3), STAGE_B0(1, kt0 + 3), VM4);
    }
    // tail: tile 62 finishes tile 63's halves then drains; tile 63 no issues
    FULL_TILE(0, STAGE_B1(1, 63), STAGE_A1(1, 63), , , VM0);
    FULL_TILE(1, , , , , );
    VM0;

    // ---- epilogue: per-wave LDS transpose (stride 68, proven pattern), scaled f32 stores ----
    // C/D frag layout: col=lane&15 (N), row=(lane>>4)*4+reg (M).
    float* epi = (float*)(lds + wave * 4352);   // 16 rows x stride 68 floats
    const int cn = lane & 15, qd = lane >> 4;
    float scl[2][2];
    #pragma unroll
    for (int hb = 0; hb < 2; ++hb)
        #pragma unroll
        for (int ni = 0; ni < 2; ++ni)
            scl[hb][ni] = scales[n0 + hb * 128 + wc * 32 + ni * 16 + cn];

    // local col L=0..63 <-> global col n0 + 32*wc + 96*hb + L  (two 128B islands per row)
    const int colb = n0 + wc * 32 + ((cn >= 8) ? (128 + (cn - 8) * 4) : cn * 4);

    #pragma unroll
    for (int ha = 0; ha < 2; ++ha)
        #pragma unroll
        for (int mi = 0; mi < 4; ++mi) {
            #pragma unroll
            for (int hb = 0; hb < 2; ++hb)
                #pragma unroll
                for (int ni = 0; ni < 2; ++ni)
                    #pragma unroll
                    for (int r = 0; r < 4; ++r)
                        epi[(qd * 4 + r) * 68 + hb * 32 + ni * 16 + cn] =
                            acc[ha][hb][mi][ni][r] * scl[hb][ni];
            const int rowb = m0 + ha * 128 + wr * 64 + mi * 16;
            #pragma unroll
            for (int p = 0; p < 4; ++p) {
                float4 vv = *(const float4*)&epi[(p * 4 + qd) * 68 + cn * 4];
                *(float4*)&out[(size_t)(rowb + p * 4 + qd) * N_DIM + colb] = vv;
            }
        }
}

extern "C" void kernel_launch(void* const* d_in, const int* in_sizes, int n_in,
                              void* d_out, int out_size, void* d_ws, size_t ws_size,
                              hipStream_t stream) {
    const float* x = (const float*)d_in[0];
    const float* w = (const float*)d_in[1];
    float* out = (float*)d_out;

    char* ws = (char*)d_ws;
    __hip_bfloat16* xb = (__hip_bfloat16*)ws;
    __hip_bfloat16* qb = (__hip_bfloat16*)(ws + (size_t)M_DIM * K_DIM * 2);
    float* scales = (float*)(ws + (size_t)M_DIM * K_DIM * 2 + (size_t)N_DIM * K_DIM * 2);

    fused_scale_quant<<<N_DIM, 256, 0, stream>>>(w, scales, qb);
    xconv_kernel<<<(M_DIM * K_DIM / 8) / 256, 256, 0, stream>>>(x, xb);
    gemm_kernel<<<(M_DIM / 256) * (N_DIM / 256), 512, 0, stream>>>(xb, qb, scales, out);
}